// Round 17
// baseline (55.343 us; speedup 1.0000x reference)
//
#include <hip/hip_runtime.h>

typedef _Float16 f16;
typedef __attribute__((ext_vector_type(2))) __fp16 fp16x2;
typedef __attribute__((ext_vector_type(8))) _Float16 f16x8;
typedef __attribute__((ext_vector_type(16))) float f32x16;
typedef __attribute__((ext_vector_type(4))) unsigned int u32x4;

#define NPTS (16 * 32768)
// packed-weight frag layout (32x32x16 fragments, 1KB each = 64 lanes x 16B)
#define W0F 0                  // 16 frags (4 mt x 4 kt)   16KB
#define W1F (16 * 1024)        // 32 frags (4 mt x 8 kt)   32KB
#define W2F (48 * 1024)        // 32 frags                 32KB
#define WOF (80 * 1024)        // 8 frags (8 kt)           8KB
#define FRAGS_BYTES (88 * 1024)
#define TENC_OFF FRAGS_BYTES   // ws: 16 batches x 16 f32
#define WS_NEEDED (FRAGS_BYTES + 1024)
#define LDS_TOTAL 4096         // single-wave block: one 4KB transpose scratch

// k-position maps within a 16-wide kt block (h = lane>>5, j = elem 0..7):
//   natural (layer0, matches feature build):  k = 8h + j
//   chained (layers 1,2,out, from D layout):  k = (j&3) + 8*(j>>2) + 4h
// D(32x32) layout: col = lane&31, row = (r&3) + 8*(r>>2) + 4*(lane>>5), r=0..15.
// Chain: Bout frag kt'=2mt+f elem j := D reg r=8f+j -> row = 16f + kperm(h,j)
//   -> global k = 32mt + 16f + kperm = 16*kt' + kperm. (verified r14, absmax 2.44e-4)
__global__ void pack_weights(const float* __restrict__ time, const float* __restrict__ te0,
                             const float* __restrict__ te1, const float* __restrict__ W0,
                             const float* __restrict__ W1, const float* __restrict__ W2,
                             const float* __restrict__ Wout, unsigned char* __restrict__ ws) {
  const int bi = blockIdx.x;
  const int l = threadIdx.x;
  const int h = l >> 5, r32 = l & 31;
  if (bi < 88) {
    const float* W; int obase, mt, kt, kmax; bool natural, outcol;
    if (bi < 16)      { W = W0;   mt = bi >> 2;        kt = bi & 3;  obase = W0F; kmax = 55;  natural = true;  outcol = false; }
    else if (bi < 48) { W = W1;   mt = (bi - 16) >> 3; kt = (bi - 16) & 7; obase = W1F; kmax = 128; natural = false; outcol = false; }
    else if (bi < 80) { W = W2;   mt = (bi - 48) >> 3; kt = (bi - 48) & 7; obase = W2F; kmax = 128; natural = false; outcol = false; }
    else              { W = Wout; mt = 0;              kt = bi - 80; obase = WOF; kmax = 128; natural = false; outcol = true;  }
    const int m = mt * 32 + r32;
    const int fi = outcol ? kt : (bi < 16 ? mt * 4 + kt : mt * 8 + kt);
    f16 vals[8] __attribute__((aligned(16)));
#pragma unroll
    for (int j = 0; j < 8; ++j) {
      const int kl = natural ? (8 * h + j) : ((j & 3) + 8 * (j >> 2) + 4 * h);
      const int k = kt * 16 + kl;
      float v = 0.f;
      if (k < kmax) v = outcol ? ((r32 == 0) ? Wout[k] : 0.f) : W[k * 128 + m];
      vals[j] = (f16)v;
    }
    *(u32x4*)(ws + obase + (fi * 64 + l) * 16) = *(const u32x4*)vals;
  } else {
    // time encoding: 16 batches x 16 dims fp32
    const int idx = (bi - 88) * 64 + l;  // 0..255
    const int b = idx >> 4, d = idx & 15;
    const float t = time[b];
    const float* emb; int L, dd;
    if (d < 8) { emb = te0; L = 5;  dd = d; }
    else       { emb = te1; L = 20; dd = d - 8; }
    const float tL = t * (float)L;
    int i = (int)floorf(tL);
    i = i < 0 ? 0 : (i > L - 1 ? L - 1 : i);
    const float wlo = (float)(i + 1) - tL;
    float v = wlo * emb[i * 8 + dd] + (1.f - wlo) * emb[(i + 1) * 8 + dd];
    if (t >= 1.f) v = emb[L * 8 + dd];
    ((float*)(ws + TENC_OFF))[idx] = v;
  }
}

// packed relu: max of two f16 halves vs 0 (exact: relu commutes with RTZ rounding)
__device__ __forceinline__ unsigned int pkmax0(unsigned int x) {
  unsigned int r;
  asm("v_pk_max_f16 %0, %1, %2" : "=v"(r) : "v"(x), "v"(0u));
  return r;
}
__device__ __forceinline__ unsigned int pkrtz(float a, float b) {
  union { fp16x2 h; unsigned int u; } c;
  c.h = __builtin_amdgcn_cvt_pkrtz(a, b);
  return c.u;
}

// ---------------- one layer, 32x32x16: D = W_sw(128xK) * B(Kx64), weights from L2 ----------------
// Flattened (mt,kt) step stream, one 1KB A-frag per step feeding both n-half MFMAs;
// 2-deep / 3-slot rotating prefetch. Bias rides as the MFMA C-init (f32x16).
template <int KT>
__device__ __forceinline__ void layer32(const unsigned char* __restrict__ wsrc,
                                        const float* __restrict__ bias,
                                        const f16x8 (&Bin)[2][KT], f16x8 (&Bout)[2][8],
                                        int lane) {
  const int h = lane >> 5;
  f16x8 Ab[3];
  Ab[0] = *(const f16x8*)(wsrc + (0 * 64 + lane) * 16);
  Ab[1] = *(const f16x8*)(wsrc + (1 * 64 + lane) * 16);
#pragma unroll
  for (int mt = 0; mt < 4; ++mt) {
    f32x16 c;
#pragma unroll
    for (int q = 0; q < 4; ++q) {
      const float4 b4 = *(const float4*)(bias + mt * 32 + q * 8 + 4 * h);
      c[4 * q] = b4.x; c[4 * q + 1] = b4.y; c[4 * q + 2] = b4.z; c[4 * q + 3] = b4.w;
    }
    f32x16 a0 = c, a1 = c;
#pragma unroll
    for (int kt = 0; kt < KT; ++kt) {
      const int s = mt * KT + kt, cb = s % 3;
      if (s + 2 < 4 * KT) {
        const int s2 = s + 2, pb = s2 % 3;
        Ab[pb] = *(const f16x8*)(wsrc + (s2 * 64 + lane) * 16);
      }
      __builtin_amdgcn_s_setprio(1);
      a0 = __builtin_amdgcn_mfma_f32_32x32x16_f16(Ab[cb], Bin[0][kt], a0, 0, 0, 0);
      a1 = __builtin_amdgcn_mfma_f32_32x32x16_f16(Ab[cb], Bin[1][kt], a1, 0, 0, 0);
      __builtin_amdgcn_s_setprio(0);
    }
#pragma unroll
    for (int f = 0; f < 2; ++f) {
      union { unsigned int w[4]; f16x8 v; } u0, u1;
#pragma unroll
      for (int pq = 0; pq < 4; ++pq) {
        u0.w[pq] = pkmax0(pkrtz(a0[8 * f + 2 * pq], a0[8 * f + 2 * pq + 1]));
        u1.w[pq] = pkmax0(pkrtz(a1[8 * f + 2 * pq], a1[8 * f + 2 * pq + 1]));
      }
      Bout[0][2 * mt + f] = u0.v;
      Bout[1][2 * mt + f] = u1.v;
    }
  }
}

// ---------------- fused main kernel: 1-wave blocks, 32x32 MFMA, weights from L2 ----------------
// (64,1): unconstrained VGPR budget (allocator law: budget = 2048/(waves x min_blocks);
// min_blocks>1 re-caps at 64 and spills — r15). 32x32 halves MFMA instruction count
// (336->176) vs the 16x16 chain at identical weight bytes.
__global__ void __launch_bounds__(64, 1)
mlp_main(const float* __restrict__ xyz, const float* __restrict__ b0,
         const float* __restrict__ b1, const float* __restrict__ b2,
         const float* __restrict__ bout, const unsigned char* __restrict__ ws,
         float* __restrict__ out) {
  extern __shared__ char lds[];
  const int lane = threadIdx.x;
  const int h = lane >> 5, r32 = lane & 31;

  char* scr = lds;  // this wave's transpose scratch (32 rows x 128B)
  const float bo = bout[0];

  const int pbase = blockIdx.x * 64;
  const int p = pbase + lane;

  // ---- 64-dim feature row in f32, then pack pairs with cvt_pkrtz ----
  float ff[64];
  const float* tb = (const float*)(ws + TENC_OFF) + (blockIdx.x >> 9) * 16;  // batch = p/32768
#pragma unroll
  for (int i = 0; i < 16; ++i) ff[i] = tb[i];
  const float xs0 = xyz[p * 3], xs1 = xyz[p * 3 + 1], xs2 = xyz[p * 3 + 2];
  const float pcs[3] = {(xs0 + 1.f) * 0.5f, (xs1 + 1.f) * 0.5f, (xs2 + 1.f) * 0.5f};
#pragma unroll
  for (int c = 0; c < 3; ++c) {
    ff[16 + c] = pcs[c];
    float s = __sinf(pcs[c]), co = __cosf(pcs[c]);
#pragma unroll
    for (int f = 0; f < 6; ++f) {
      ff[19 + f * 3 + c] = s;
      ff[37 + f * 3 + c] = co;
      const float s2 = 2.f * s * co, c2 = 1.f - 2.f * s * s;
      s = s2; co = c2;
    }
  }
#pragma unroll
  for (int i = 55; i < 64; ++i) ff[i] = 0.f;
  unsigned int fw[32];
#pragma unroll
  for (int i = 0; i < 32; ++i) fw[i] = pkrtz(ff[2 * i], ff[2 * i + 1]);

  // ---- transpose via scratch, two 32-point halves -> B0 fragments (natural k-map) ----
  // B0[nh][kt] elem (h,j) = feat[32nh + r32][16kt + 8h + j]
  f16x8 B0[2][4];
#pragma unroll
  for (int nh = 0; nh < 2; ++nh) {
    if (h == nh) {
#pragma unroll
      for (int s = 0; s < 8; ++s)
        *(u32x4*)(scr + r32 * 128 + ((s ^ (r32 & 7)) * 16)) = ((const u32x4*)fw)[s];
    }
    asm volatile("s_waitcnt lgkmcnt(0)" ::: "memory");
#pragma unroll
    for (int kt = 0; kt < 4; ++kt)
      B0[nh][kt] = *(const f16x8*)(scr + r32 * 128 + (((2 * kt + h) ^ (r32 & 7)) * 16));
    asm volatile("s_waitcnt lgkmcnt(0)" ::: "memory");
  }

  // ---- 3 hidden layers, register-chained, weights streamed from L2 ----
  f16x8 Bx[2][8], By[2][8];
  layer32<4>(ws + W0F, b0, B0, Bx, lane);
  layer32<8>(ws + W1F, b1, Bx, By, lane);
  layer32<8>(ws + W2F, b2, By, Bx, lane);

  // ---- output layer: M=32 padded (row 0 real), preload all 8 frags, 16 MFMAs ----
  f16x8 Ob[8];
#pragma unroll
  for (int kt = 0; kt < 8; ++kt)
    Ob[kt] = *(const f16x8*)(ws + WOF + (kt * 64 + lane) * 16);
  f32x16 o0, o1;
#pragma unroll
  for (int r = 0; r < 16; ++r) { o0[r] = bo; o1[r] = bo; }
  __builtin_amdgcn_s_setprio(1);
#pragma unroll
  for (int kt = 0; kt < 8; ++kt) {
    o0 = __builtin_amdgcn_mfma_f32_32x32x16_f16(Ob[kt], Bx[0][kt], o0, 0, 0, 0);
    o1 = __builtin_amdgcn_mfma_f32_32x32x16_f16(Ob[kt], Bx[1][kt], o1, 0, 0, 0);
  }
  __builtin_amdgcn_s_setprio(0);

  // row 0 lives in reg 0 of lanes 0..31 (h=0): two 128B half-wave stores
  if (lane < 32) {
    out[pbase + lane] = o0[0];
    out[pbase + 32 + lane] = o1[0];
  }
}

extern "C" void kernel_launch(void* const* d_in, const int* in_sizes, int n_in,
                              void* d_out, int out_size, void* d_ws, size_t ws_size,
                              hipStream_t stream) {
  const float* time = (const float*)d_in[0];
  const float* xyz  = (const float*)d_in[1];
  const float* te0  = (const float*)d_in[2];
  const float* te1  = (const float*)d_in[3];
  const float* W0   = (const float*)d_in[4];
  const float* b0   = (const float*)d_in[5];
  const float* W1   = (const float*)d_in[6];
  const float* b1   = (const float*)d_in[7];
  const float* W2   = (const float*)d_in[8];
  const float* b2   = (const float*)d_in[9];
  const float* Wout = (const float*)d_in[10];
  const float* bout = (const float*)d_in[11];
  float* out = (float*)d_out;
  unsigned char* ws = (unsigned char*)d_ws;
  if (ws_size < WS_NEEDED) return;

  pack_weights<<<92, 64, 0, stream>>>(time, te0, te1, W0, W1, W2, Wout, ws);
  mlp_main<<<NPTS / 64, 64, LDS_TOTAL, stream>>>(xyz, b0, b1, b2, bout, ws, out);
}

// Round 18
// 46.869 us; speedup vs baseline: 1.1808x; 1.1808x over previous
//
#include <hip/hip_runtime.h>

typedef _Float16 f16;
typedef __attribute__((ext_vector_type(2))) __fp16 fp16x2;
typedef __attribute__((ext_vector_type(8))) _Float16 f16x8;
typedef __attribute__((ext_vector_type(4))) float f32x4;
typedef __attribute__((ext_vector_type(4))) unsigned int u32x4;

#define NPTS   (16 * 32768)
// packed-weight layout in d_ws (bytes); weights stay in global (L2-resident, ~80KB)
#define W0P_OFF 0
#define W1P_OFF (16 * 1024)
#define W2P_OFF (48 * 1024)
#define WOP_OFF (80 * 1024)
#define FRAGS_BYTES (84 * 1024)
#define B0E_OFF FRAGS_BYTES           // in ws: 16 batches x 128 f32 effective layer-0 bias
#define WS_NEEDED (FRAGS_BYTES + 8192)
// LDS: one wave per block -> single 4KB transpose scratch
#define LDS_TOTAL 4096

// ---------------- pack kernel: weights -> f16 A-operand fragments (W^T) ----------------
// A frag (mt,kt): lane l, elem j <-> W_sw[m = 16mt + (l&15)][k] = W[k][m]
//   layer0 (natural k-map, matches layer-0 B build): k = 32kt + 8*(l>>4) + j
//     NEW: layer-0 K covers only the 39 xyz-derived dims; orig W0 row = 16 + k.
//     tenc (orig rows 0..15) is folded into b0_eff per batch (blocks 84..115).
//   layers 1,2,out (chained from D layout):          k = 32kt + 16*(j>>2) + 4*(l>>4) + (j&3)
__global__ void pack_weights(const float* __restrict__ time, const float* __restrict__ te0,
                             const float* __restrict__ te1, const float* __restrict__ W0,
                             const float* __restrict__ b0, const float* __restrict__ W1,
                             const float* __restrict__ W2, const float* __restrict__ Wout,
                             unsigned char* __restrict__ ws) {
  const int bi = blockIdx.x;
  const int l = threadIdx.x;
  const int g = l >> 4, r16 = l & 15;
  if (bi < 84) {
    const float* W; int obase, fi, kt, mt, kmax; bool natural, outcol;
    if (bi < 16)      { W = W0;   fi = bi;      mt = fi >> 1; kt = fi & 1; obase = W0P_OFF; kmax = 39;  natural = true;  outcol = false; }
    else if (bi < 48) { W = W1;   fi = bi - 16; mt = fi >> 2; kt = fi & 3; obase = W1P_OFF; kmax = 128; natural = false; outcol = false; }
    else if (bi < 80) { W = W2;   fi = bi - 48; mt = fi >> 2; kt = fi & 3; obase = W2P_OFF; kmax = 128; natural = false; outcol = false; }
    else              { W = Wout; fi = bi - 80; mt = 0;       kt = fi;     obase = WOP_OFF; kmax = 128; natural = false; outcol = true;  }
    const int m = mt * 16 + r16;
    f16 vals[8] __attribute__((aligned(16)));
#pragma unroll
    for (int j = 0; j < 8; ++j) {
      const int k = natural ? (kt * 32 + g * 8 + j)
                            : (kt * 32 + (j >> 2) * 16 + g * 4 + (j & 3));
      float v = 0.f;
      if (k < kmax) {
        if (outcol)       v = (m == 0) ? Wout[k] : 0.f;
        else if (natural) v = W[(16 + k) * 128 + m];   // layer0: skip tenc rows
        else              v = W[k * 128 + m];
      }
      vals[j] = (f16)v;
    }
    *(u32x4*)(ws + obase + (fi * 64 + l) * 16) = *(const u32x4*)vals;
  } else {
    // b0_eff[b][m] = b0[m] + sum_d tenc[b][d] * W0[d][m],  d = 0..15 (orig rows)
    const int idx = (bi - 84) * 64 + l;  // 0..2047
    const int b = idx >> 7, m = idx & 127;
    const float t = time[b];
    float acc = b0[m];
#pragma unroll
    for (int d = 0; d < 16; ++d) {
      const float* emb; int L, dd;
      if (d < 8) { emb = te0; L = 5;  dd = d; }
      else       { emb = te1; L = 20; dd = d - 8; }
      const float tL = t * (float)L;
      int i = (int)floorf(tL);
      i = i < 0 ? 0 : (i > L - 1 ? L - 1 : i);
      const float wlo = (float)(i + 1) - tL;
      float v = wlo * emb[i * 8 + dd] + (1.f - wlo) * emb[(i + 1) * 8 + dd];
      if (t >= 1.f) v = emb[L * 8 + dd];
      acc += v * W0[d * 128 + m];
    }
    ((float*)(ws + B0E_OFF))[b * 128 + m] = acc;
  }
}

// packed relu: max of two f16 halves vs 0 (exact: relu commutes with RTZ rounding)
__device__ __forceinline__ unsigned int pkmax0(unsigned int x) {
  unsigned int r;
  asm("v_pk_max_f16 %0, %1, %2" : "=v"(r) : "v"(x), "v"(0u));
  return r;
}
__device__ __forceinline__ unsigned int pkrtz(float a, float b) {
  union { fp16x2 h; unsigned int u; } c;
  c.h = __builtin_amdgcn_cvt_pkrtz(a, b);
  return c.u;
}
// HW transcendentals: v_sin/v_cos take revolutions (input * 2pi). x in [0,1] here.
__device__ __forceinline__ float hwsin_rev(float rev) {
  float r; asm("v_sin_f32 %0, %1" : "=v"(r) : "v"(rev)); return r;
}
__device__ __forceinline__ float hwcos_rev(float rev) {
  float r; asm("v_cos_f32 %0, %1" : "=v"(r) : "v"(rev)); return r;
}

// ---------------- one swapped hidden layer: D = W_sw(128xK) * Bin(Kx64) ----------------
// A-frags stream from L2 with the r8 2-deep rotating prefetch. Bias loaded at kt==0,
// applied via C-init; epilogue = pkrtz + pk_max.
template <int KT>
__device__ __forceinline__ void layer_swapped(const unsigned char* __restrict__ wsrc,
                                              const float* __restrict__ bias,
                                              const f16x8 (&Bin)[KT][4], f16x8 (&Bout)[4][4],
                                              int lane) {
  const int g4 = (lane >> 4) * 4;
  f16x8 A0b[3], A1b[3];
  float4 ba, bb;
  f32x4 acc[2][4];
  // prologue: preload steps 0,1
#pragma unroll
  for (int s = 0; s < 2; ++s) {
    const int mtp = s / KT, kt = s % KT;
    A0b[s] = *(const f16x8*)(wsrc + (((2 * mtp)     * KT + kt) * 64 + lane) * 16);
    A1b[s] = *(const f16x8*)(wsrc + (((2 * mtp + 1) * KT + kt) * 64 + lane) * 16);
  }
#pragma unroll
  for (int s = 0; s < 4 * KT; ++s) {
    const int mtp = s / KT, kt = s % KT, cb = s % 3;
    if (kt == 0) {
      ba = *(const float4*)(bias + mtp * 32 + g4);
      bb = *(const float4*)(bias + mtp * 32 + 16 + g4);
#pragma unroll
      for (int nt = 0; nt < 4; ++nt) {
        acc[0][nt] = (f32x4){ba.x, ba.y, ba.z, ba.w};
        acc[1][nt] = (f32x4){bb.x, bb.y, bb.z, bb.w};
      }
    }
    // prefetch step s+2
    if (s + 2 < 4 * KT) {
      const int mtp2 = (s + 2) / KT, kt2 = (s + 2) % KT, pb = (s + 2) % 3;
      A0b[pb] = *(const f16x8*)(wsrc + (((2 * mtp2)     * KT + kt2) * 64 + lane) * 16);
      A1b[pb] = *(const f16x8*)(wsrc + (((2 * mtp2 + 1) * KT + kt2) * 64 + lane) * 16);
    }
    __builtin_amdgcn_s_setprio(1);
#pragma unroll
    for (int nt = 0; nt < 4; ++nt)
      acc[0][nt] = __builtin_amdgcn_mfma_f32_16x16x32_f16(A0b[cb], Bin[kt][nt], acc[0][nt], 0, 0, 0);
#pragma unroll
    for (int nt = 0; nt < 4; ++nt)
      acc[1][nt] = __builtin_amdgcn_mfma_f32_16x16x32_f16(A1b[cb], Bin[kt][nt], acc[1][nt], 0, 0, 0);
    __builtin_amdgcn_s_setprio(0);
    if (kt == KT - 1) {
#pragma unroll
      for (int nt = 0; nt < 4; ++nt) {
        union { unsigned int w[4]; f16x8 v; } u;
        u.w[0] = pkmax0(pkrtz(acc[0][nt][0], acc[0][nt][1]));
        u.w[1] = pkmax0(pkrtz(acc[0][nt][2], acc[0][nt][3]));
        u.w[2] = pkmax0(pkrtz(acc[1][nt][0], acc[1][nt][1]));
        u.w[3] = pkmax0(pkrtz(acc[1][nt][2], acc[1][nt][3]));
        Bout[mtp][nt] = u.v;
      }
    }
  }
}

// ---------------- fused main kernel: SINGLE-WAVE blocks (64 thr), weights from L2 ----------------
// (64,1): unconstrained VGPR budget (allocator law: budget = 2048/(waves x min_blocks);
// any min_blocks>1 re-caps VGPR at 64 and spills — r15).
__global__ void __launch_bounds__(64, 1)
mlp_main(const float* __restrict__ xyz, const float* __restrict__ b1,
         const float* __restrict__ b2, const float* __restrict__ bout,
         const unsigned char* __restrict__ ws, float* __restrict__ out) {
  extern __shared__ char lds[];
  const int lane = threadIdx.x;
  const int g = lane >> 4, r16 = lane & 15;

  char* scr = lds;  // this wave's private transpose scratch (32 rows x 128B)
  const float bo = bout[0];

  const int pbase = blockIdx.x * 64;
  const int p = pbase + lane;

  // ---- 39-dim xyz feature row in f32 (tenc folded into b0_eff), pack with cvt_pkrtz ----
  // new dim order: [pts(3), sin(18), cos(18)], zeros to 64. orig W0 row = 16 + dim.
  float ff[40];
  const float xs0 = xyz[p * 3], xs1 = xyz[p * 3 + 1], xs2 = xyz[p * 3 + 2];
  const float pcs[3] = {(xs0 + 1.f) * 0.5f, (xs1 + 1.f) * 0.5f, (xs2 + 1.f) * 0.5f};
  const float INV2PI = 0.15915494309189535f;
#pragma unroll
  for (int c = 0; c < 3; ++c) {
    ff[c] = pcs[c];
    const float rev = pcs[c] * INV2PI;
    float s = hwsin_rev(rev), co = hwcos_rev(rev);
#pragma unroll
    for (int f = 0; f < 6; ++f) {
      ff[3 + f * 3 + c] = s;
      ff[21 + f * 3 + c] = co;
      const float s2 = 2.f * s * co, c2 = 1.f - 2.f * s * s;
      s = s2; co = c2;
    }
  }
  ff[39] = 0.f;
  unsigned int fw[32];
#pragma unroll
  for (int i = 0; i < 20; ++i) fw[i] = pkrtz(ff[2 * i], ff[2 * i + 1]);
#pragma unroll
  for (int i = 20; i < 32; ++i) fw[i] = 0u;

  // ---- transpose via scratch, two 32-point halves (wave-internal sync) ----
  f16x8 B0[2][4];
#pragma unroll
  for (int h = 0; h < 2; ++h) {
    if ((lane >> 5) == h) {
#pragma unroll
      for (int s = 0; s < 8; ++s)
        *(u32x4*)(scr + (lane & 31) * 128 + ((s ^ (lane & 7)) * 16)) = ((const u32x4*)fw)[s];
    }
    asm volatile("s_waitcnt lgkmcnt(0)" ::: "memory");
#pragma unroll
    for (int kt = 0; kt < 2; ++kt)
#pragma unroll
      for (int nn = 0; nn < 2; ++nn) {
        const int row = nn * 16 + r16;
        B0[kt][h * 2 + nn] = *(const f16x8*)(scr + row * 128 + (((4 * kt + g) ^ (row & 7)) * 16));
      }
    asm volatile("s_waitcnt lgkmcnt(0)" ::: "memory");
  }

  // ---- 3 hidden layers fully in registers, weights streamed from L2 w/ prefetch ----
  const float* b0e = (const float*)(ws + B0E_OFF) + (blockIdx.x >> 9) * 128;  // batch = p/32768
  f16x8 Bx[4][4], By[4][4];
  layer_swapped<2>(ws + W0P_OFF, b0e, B0, Bx, lane);
  layer_swapped<4>(ws + W1P_OFF, b1, Bx, By, lane);
  layer_swapped<4>(ws + W2P_OFF, b2, By, Bx, lane);

  // ---- output layer (M=16 padded, only row 0 real): preload all 4 frags, bias as C ----
  f16x8 Ab[4];
#pragma unroll
  for (int kt = 0; kt < 4; ++kt)
    Ab[kt] = *(const f16x8*)(ws + WOP_OFF + (kt * 64 + lane) * 16);
  const f32x4 bovec = (f32x4){bo, bo, bo, bo};
  f32x4 accO[4];
  __builtin_amdgcn_s_setprio(1);
#pragma unroll
  for (int nt = 0; nt < 4; ++nt)
    accO[nt] = __builtin_amdgcn_mfma_f32_16x16x32_f16(Ab[0], Bx[0][nt], bovec, 0, 0, 0);
#pragma unroll
  for (int kt = 1; kt < 4; ++kt) {
#pragma unroll
    for (int nt = 0; nt < 4; ++nt)
      accO[nt] = __builtin_amdgcn_mfma_f32_16x16x32_f16(Ab[kt], Bx[kt][nt], accO[nt], 0, 0, 0);
  }
  __builtin_amdgcn_s_setprio(0);

  // ---- coalesced store: broadcast row-0 values, one 256B wave store ----
  const float a0 = __shfl(accO[0][0], r16, 64);
  const float a1 = __shfl(accO[1][0], r16, 64);
  const float a2 = __shfl(accO[2][0], r16, 64);
  const float a3 = __shfl(accO[3][0], r16, 64);
  const float v = g == 0 ? a0 : g == 1 ? a1 : g == 2 ? a2 : a3;
  out[pbase + lane] = v;
}

extern "C" void kernel_launch(void* const* d_in, const int* in_sizes, int n_in,
                              void* d_out, int out_size, void* d_ws, size_t ws_size,
                              hipStream_t stream) {
  const float* time = (const float*)d_in[0];
  const float* xyz  = (const float*)d_in[1];
  const float* te0  = (const float*)d_in[2];
  const float* te1  = (const float*)d_in[3];
  const float* W0   = (const float*)d_in[4];
  const float* b0   = (const float*)d_in[5];
  const float* W1   = (const float*)d_in[6];
  const float* b1   = (const float*)d_in[7];
  const float* W2   = (const float*)d_in[8];
  const float* b2   = (const float*)d_in[9];
  const float* Wout = (const float*)d_in[10];
  const float* bout = (const float*)d_in[11];
  float* out = (float*)d_out;
  unsigned char* ws = (unsigned char*)d_ws;
  if (ws_size < WS_NEEDED) return;

  // 84 weight-frag blocks + 32 blocks computing b0_eff (16 batches x 128)
  pack_weights<<<116, 64, 0, stream>>>(time, te0, te1, W0, b0, W1, W2, Wout, ws);
  mlp_main<<<NPTS / 64, 64, LDS_TOTAL, stream>>>(xyz, b1, b2, bout, ws, out);
}